// Round 10
// baseline (378.763 us; speedup 1.0000x reference)
//
#include <hip/hip_runtime.h>
#include <hip/hip_bf16.h>

#define Hh    128
#define NINc  384
#define KN    48
#define FFd   512
#define NNODE 8192
#define NPB   32            // nodes per persistent edge block
#define EGRID (NNODE/NPB)   // 256 blocks = 1/CU

typedef __attribute__((ext_vector_type(8))) short short8v;
typedef __attribute__((ext_vector_type(4))) float f32x4;

__device__ __forceinline__ short f2bf1(float f){
  union { __hip_bfloat16 h; short s; } c; c.h = __float2bfloat16(f);
  return c.s;
}
__device__ __forceinline__ unsigned pk_bf16(float lo, float hi){
  union { __hip_bfloat162 h; unsigned u; } c;
  c.h = __float22bfloat162_rn(make_float2(lo, hi));
  return c.u;
}

// 0.5x(1+tanh(t)) == x*sigmoid(2t); max dev from erf-GELU ~3e-4
__device__ __forceinline__ float gelu_f(float x){
  float t = 0.7978845608028654f * x * (1.0f + 0.044715f * x * x);
  float e = __expf(2.0f * t);
  return x * (1.0f - 1.0f / (e + 1.0f));
}

// LDS-publish barrier WITHOUT vmem drain (prefetch loads stay in flight)
__device__ __forceinline__ void bar_lds(){
  asm volatile("s_waitcnt lgkmcnt(0)\n\ts_barrier" ::: "memory");
}

// ---------------- weight prep ----------------
// w1vT: [128 out][128 in] (np_kernel). w1p/w2p/w3p fragment-packed:
// [ntile][ks][lane][8] bf16 -> one wave frag = 1 contiguous KB.
__global__ void prep_weights(const float* __restrict__ W1, const float* __restrict__ W2,
                             const float* __restrict__ W3, const float* __restrict__ Win,
                             const float* __restrict__ Wout,
                             short* __restrict__ w1vT, short* __restrict__ w1p,
                             short* __restrict__ w2p,  short* __restrict__ w3p,
                             short* __restrict__ winT, short* __restrict__ woutT)
{
  int i = blockIdx.x * 256 + threadIdx.x;
  if (i < 16384){ int n = i / 128, k = i % 128; w1vT[i] = f2bf1(W1[k*128 + n]); return; }
  i -= 16384;
  if (i < 49152){ // w1p: n<8, ks<12
    int n = i / 6144, r = i % 6144;
    int ks = r / 512, r2 = r % 512;
    int lane = r2 / 8, j = r2 % 8;
    int qq = lane >> 4, arow = lane & 15;
    w1p[i] = f2bf1(W1[(128 + ks*32 + qq*8 + j)*128 + n*16 + arow]); return;
  }
  i -= 49152;
  if (i < 16384){ // w2p: n<8, ks<4
    int n = i / 2048, r = i % 2048;
    int ks = r / 512, r2 = r % 512;
    int lane = r2 / 8, j = r2 % 8;
    int qq = lane >> 4, arow = lane & 15;
    w2p[i] = f2bf1(W2[(ks*32 + qq*8 + j)*128 + n*16 + arow]); return;
  }
  i -= 16384;
  if (i < 16384){ // w3p
    int n = i / 2048, r = i % 2048;
    int ks = r / 512, r2 = r % 512;
    int lane = r2 / 8, j = r2 % 8;
    int qq = lane >> 4, arow = lane & 15;
    w3p[i] = f2bf1(W3[(ks*32 + qq*8 + j)*128 + n*16 + arow]); return;
  }
  i -= 16384;
  if (i < 65536){ int n = i / 128, k = i % 128; winT[i] = f2bf1(Win[k*512 + n]); return; }
  i -= 65536;
  if (i < 65536){ int n = i / 512, k = i % 512; woutT[i] = f2bf1(Wout[k*128 + n]); return; }
}

// ---------------- node_part = h_V @ W1[:128,:] + b1  (256 blocks, 32 rows) ----
__global__ __launch_bounds__(256,4) void np_kernel(
    const float* __restrict__ hV, const short* __restrict__ w1vT,
    const float* __restrict__ b1, float* __restrict__ npart)
{
  const int row0 = blockIdx.x * 32;
  const int tid = threadIdx.x, lane = tid & 63, wv = tid >> 6;
  __shared__ __attribute__((aligned(16))) short Xs[32][Hh + 8];

  const float4* src = (const float4*)(hV + (size_t)row0 * Hh);
  #pragma unroll
  for (int j = 0; j < 4; ++j){
    int idx = tid + 256*j;
    int r = idx >> 5, c4 = idx & 31;
    float4 v = src[idx];
    *(uint2*)&Xs[r][c4*4] = make_uint2(pk_bf16(v.x,v.y), pk_bf16(v.z,v.w));
  }
  __syncthreads();

  const int arow = lane & 15, kgrp = (lane >> 4) * 8;
  const int col0 = wv * 32, ccol = lane & 15, crow0 = (lane >> 4) * 4;

  f32x4 acc[2][2];
  #pragma unroll
  for (int m = 0; m < 2; ++m) for (int n = 0; n < 2; ++n) acc[m][n] = (f32x4){0.f,0.f,0.f,0.f};

  const short8v* Bw = (const short8v*)w1vT;
  #pragma unroll
  for (int ks = 0; ks < 4; ++ks){
    int kb = ks*32 + kgrp;
    short8v b0 = Bw[(col0 + arow)*16      + (kb >> 3)];
    short8v b1f = Bw[(col0 + 16 + arow)*16 + (kb >> 3)];
    #pragma unroll
    for (int m = 0; m < 2; ++m){
      short8v a = *(const short8v*)&Xs[m*16 + arow][kb];
      acc[m][0] = __builtin_amdgcn_mfma_f32_16x16x32_bf16(a, b0,  acc[m][0], 0,0,0);
      acc[m][1] = __builtin_amdgcn_mfma_f32_16x16x32_bf16(a, b1f, acc[m][1], 0,0,0);
    }
  }
  #pragma unroll
  for (int m = 0; m < 2; ++m) for (int n = 0; n < 2; ++n){
    int colg = col0 + n*16 + ccol;
    float bb = b1[colg];
    #pragma unroll
    for (int r = 0; r < 4; ++r)
      npart[(size_t)(row0 + m*16 + crow0 + r)*Hh + colg] = acc[m][n][r] + bb;
  }
}

// ---------------- edge MLP: producer/consumer wave specialization ----------------
// 256 persistent blocks (1/CU), 512 thr. Waves 0-3 = consumers (MFMA, 32 cols
// each, w1 frags in regs). Waves 4-7 = producers (stream h_E: 18 float4/thread
// -> cvt -> ds_write into double-buffered Et). lgkm-only barriers: producer
// loads for node t+1 stay in flight across G1/G2 of node t; the only vmem wait
// is the producers' counted wait at their ds_write (served during G3).
__global__ __launch_bounds__(512,2) void edge_kernel(
    const float* __restrict__ hE, const float* __restrict__ hV,
    const float* __restrict__ maskA, const float* __restrict__ npart,
    const short* __restrict__ w1p, const short* __restrict__ w2p,
    const short* __restrict__ w3p,
    const float* __restrict__ b2, const float* __restrict__ b3,
    float* __restrict__ out)
{
  const int base = blockIdx.x * NPB;
  const int tid = threadIdx.x, lane = tid & 63, wv = tid >> 6;   // 0..7
  const bool cons = (wv < 4), prod = !cons;
  const int e = lane & 15, q = lane >> 4;
  const int n0 = (wv & 3) * 32;          // consumer column base
  const int tid2 = tid & 255;            // producer staging index

  __shared__ __attribute__((aligned(16))) short Et[2][KN][NINc + 8]; // 2x37632B
  __shared__ __attribute__((aligned(16))) short M1[KN][136];         // 13056B
  __shared__ __attribute__((aligned(16))) short M2[KN][136];         // 13056B

  // ---- producer state ----
  float4 pfa[9], pfb[9];
  auto LOADP = [&](int nn){
    const float4* src = (const float4*)(hE + (size_t)nn * (KN*NINc));
    #pragma unroll
    for (int j = 0; j < 9; ++j){
      pfa[j] = src[2*tid2     + 512*j];
      pfb[j] = src[2*tid2 + 1 + 512*j];
    }
  };
  auto STOREP = [&](int buf){
    #pragma unroll
    for (int j = 0; j < 9; ++j){
      int idx = 2*tid2 + 512*j;           // < 4608, even
      int r = idx / 96, c = idx - r*96;   // c even -> 16B aligned
      uint4 u;
      u.x = pk_bf16(pfa[j].x, pfa[j].y);
      u.y = pk_bf16(pfa[j].z, pfa[j].w);
      u.z = pk_bf16(pfb[j].x, pfb[j].y);
      u.w = pk_bf16(pfb[j].z, pfb[j].w);
      *(uint4*)&Et[buf][r][c*4] = u;
    }
  };

  // ---- consumer invariants: w1 fragments in registers, b2/b3 ----
  short8v w1f0[12], w1f1[12];
  float4 b2v0, b2v1, b3v0, b3v1;
  if (cons){
    const short8v* B1 = (const short8v*)w1p;
    #pragma unroll
    for (int ks = 0; ks < 12; ++ks){
      w1f0[ks] = B1[((2*(wv&3)  )*12 + ks)*64 + lane];
      w1f1[ks] = B1[((2*(wv&3)+1)*12 + ks)*64 + lane];
    }
    b2v0 = *(const float4*)(b2 + n0 + 4*q);
    b2v1 = *(const float4*)(b2 + n0 + 16 + 4*q);
    b3v0 = *(const float4*)(b3 + n0 + 4*q);
    b3v1 = *(const float4*)(b3 + n0 + 16 + 4*q);
  }

  // prologue: producers fill buf0 with node `base`, then issue base+1
  if (prod){
    LOADP(base);
    STOREP(0);               // counted vmcnt waits happen here
    LOADP(base + 1);         // in flight across the next whole iteration
  }
  bar_lds();

  const f32x4 Z = (f32x4){0.f,0.f,0.f,0.f};
  int cur = 0;

  #define WR_M(DST, ACC, ET, COLB, BV)  { short4 s;                 \
    s.x = f2bf1(gelu_f(ACC[0] + BV.x));                             \
    s.y = f2bf1(gelu_f(ACC[1] + BV.y));                             \
    s.z = f2bf1(gelu_f(ACC[2] + BV.z));                             \
    s.w = f2bf1(gelu_f(ACC[3] + BV.w));                             \
    *(short4*)&DST[16*ET + e][COLB + 4*q] = s; }

  for (int t = 0; t < NPB; ++t){
    const int node = base + t;

    float4 npv0, npv1, hvv0, hvv1;
    float mk0 = 0.f, mk1 = 0.f, mk2 = 0.f;

    // ---- G1: (Et[cur]·W1e)^T -> gelu(+np) -> M1   (consumers only) ----
    if (cons){
      npv0 = *(const float4*)(npart + (size_t)node*Hh + n0 + 4*q);
      npv1 = *(const float4*)(npart + (size_t)node*Hh + n0 + 16 + 4*q);
      mk0 = maskA[node*KN + e];
      mk1 = maskA[node*KN + 16 + e];
      mk2 = maskA[node*KN + 32 + e];
      hvv0 = *(const float4*)(hV + (size_t)node*Hh + n0 + 4*q);
      hvv1 = *(const float4*)(hV + (size_t)node*Hh + n0 + 16 + 4*q);

      f32x4 a00=Z, a10=Z, a20=Z, a01=Z, a11=Z, a21=Z;
      #pragma unroll
      for (int ks = 0; ks < 12; ++ks){
        int kb = ks*32 + q*8;
        short8v t0 = *(const short8v*)&Et[cur][e][kb];
        short8v t1 = *(const short8v*)&Et[cur][16 + e][kb];
        short8v t2 = *(const short8v*)&Et[cur][32 + e][kb];
        a00 = __builtin_amdgcn_mfma_f32_16x16x32_bf16(w1f0[ks], t0, a00, 0,0,0);
        a10 = __builtin_amdgcn_mfma_f32_16x16x32_bf16(w1f0[ks], t1, a10, 0,0,0);
        a20 = __builtin_amdgcn_mfma_f32_16x16x32_bf16(w1f0[ks], t2, a20, 0,0,0);
        a01 = __builtin_amdgcn_mfma_f32_16x16x32_bf16(w1f1[ks], t0, a01, 0,0,0);
        a11 = __builtin_amdgcn_mfma_f32_16x16x32_bf16(w1f1[ks], t1, a11, 0,0,0);
        a21 = __builtin_amdgcn_mfma_f32_16x16x32_bf16(w1f1[ks], t2, a21, 0,0,0);
      }
      WR_M(M1, a00, 0, n0,      npv0)  WR_M(M1, a10, 1, n0,      npv0)
      WR_M(M1, a20, 2, n0,      npv0)  WR_M(M1, a01, 0, n0 + 16, npv1)
      WR_M(M1, a11, 1, n0 + 16, npv1)  WR_M(M1, a21, 2, n0 + 16, npv1)
    }
    bar_lds();   // M1 visible (lgkm-only: producer loads stay in flight)

    // ---- G2: (M1·W2)^T -> gelu(+b2) -> M2   (consumers only) ----
    if (cons){
      f32x4 c00=Z, c10=Z, c20=Z, c01=Z, c11=Z, c21=Z;
      const short8v* B2f = (const short8v*)w2p;
      #pragma unroll
      for (int ks = 0; ks < 4; ++ks){
        short8v f0 = B2f[((2*(wv&3)  )*4 + ks)*64 + lane];
        short8v f1 = B2f[((2*(wv&3)+1)*4 + ks)*64 + lane];
        int kb = ks*32 + q*8;
        short8v t0 = *(const short8v*)&M1[e][kb];
        short8v t1 = *(const short8v*)&M1[16 + e][kb];
        short8v t2 = *(const short8v*)&M1[32 + e][kb];
        c00 = __builtin_amdgcn_mfma_f32_16x16x32_bf16(f0, t0, c00, 0,0,0);
        c10 = __builtin_amdgcn_mfma_f32_16x16x32_bf16(f0, t1, c10, 0,0,0);
        c20 = __builtin_amdgcn_mfma_f32_16x16x32_bf16(f0, t2, c20, 0,0,0);
        c01 = __builtin_amdgcn_mfma_f32_16x16x32_bf16(f1, t0, c01, 0,0,0);
        c11 = __builtin_amdgcn_mfma_f32_16x16x32_bf16(f1, t1, c11, 0,0,0);
        c21 = __builtin_amdgcn_mfma_f32_16x16x32_bf16(f1, t2, c21, 0,0,0);
      }
      WR_M(M2, c00, 0, n0,      b2v0)  WR_M(M2, c10, 1, n0,      b2v0)
      WR_M(M2, c20, 2, n0,      b2v0)  WR_M(M2, c01, 0, n0 + 16, b2v1)
      WR_M(M2, c11, 1, n0 + 16, b2v1)  WR_M(M2, c21, 2, n0 + 16, b2v1)
    }
    bar_lds();   // M2 visible

    // ---- G3 (consumers) || stage-write t+1 (producers) ----
    if (cons){
      f32x4 d00=Z, d10=Z, d20=Z, d01=Z, d11=Z, d21=Z;
      const short8v* B3f = (const short8v*)w3p;
      #pragma unroll
      for (int ks = 0; ks < 4; ++ks){
        short8v f0 = B3f[((2*(wv&3)  )*4 + ks)*64 + lane];
        short8v f1 = B3f[((2*(wv&3)+1)*4 + ks)*64 + lane];
        int kb = ks*32 + q*8;
        short8v t0 = *(const short8v*)&M2[e][kb];
        short8v t1 = *(const short8v*)&M2[16 + e][kb];
        short8v t2 = *(const short8v*)&M2[32 + e][kb];
        d00 = __builtin_amdgcn_mfma_f32_16x16x32_bf16(f0, t0, d00, 0,0,0);
        d10 = __builtin_amdgcn_mfma_f32_16x16x32_bf16(f0, t1, d10, 0,0,0);
        d20 = __builtin_amdgcn_mfma_f32_16x16x32_bf16(f0, t2, d20, 0,0,0);
        d01 = __builtin_amdgcn_mfma_f32_16x16x32_bf16(f1, t0, d01, 0,0,0);
        d11 = __builtin_amdgcn_mfma_f32_16x16x32_bf16(f1, t1, d11, 0,0,0);
        d21 = __builtin_amdgcn_mfma_f32_16x16x32_bf16(f1, t2, d21, 0,0,0);
      }
      f32x4 v0, v1;
      #pragma unroll
      for (int r = 0; r < 4; ++r){
        v0[r] = (d00[r] + b3v0[r])*mk0 + (d10[r] + b3v0[r])*mk1 + (d20[r] + b3v0[r])*mk2;
        v1[r] = (d01[r] + b3v1[r])*mk0 + (d11[r] + b3v1[r])*mk1 + (d21[r] + b3v1[r])*mk2;
      }
      #pragma unroll
      for (int s = 1; s <= 8; s <<= 1){
        #pragma unroll
        for (int r = 0; r < 4; ++r){
          v0[r] += __shfl_xor(v0[r], s);
          v1[r] += __shfl_xor(v1[r], s);
        }
      }
      if (e == 0){
        float4 o0, o1;
        o0.x = hvv0.x + v0[0]*(1.0f/30.0f); o0.y = hvv0.y + v0[1]*(1.0f/30.0f);
        o0.z = hvv0.z + v0[2]*(1.0f/30.0f); o0.w = hvv0.w + v0[3]*(1.0f/30.0f);
        o1.x = hvv1.x + v1[0]*(1.0f/30.0f); o1.y = hvv1.y + v1[1]*(1.0f/30.0f);
        o1.z = hvv1.z + v1[2]*(1.0f/30.0f); o1.w = hvv1.w + v1[3]*(1.0f/30.0f);
        *(float4*)(out + (size_t)node*Hh + n0 + 4*q)      = o0;
        *(float4*)(out + (size_t)node*Hh + n0 + 16 + 4*q) = o1;
      }
    }
    if (prod && t + 1 < NPB){
      STOREP(cur ^ 1);                 // counted vmcnt waits land here (during G3)
      if (t + 2 < NPB) LOADP(base + t + 2);  // next prefetch, in flight across t+1
    }
    bar_lds();   // swap: Et[cur^1] published, node t state dead
    cur ^= 1;
  }
  #undef WR_M
}

// ---------------- batched LN1 -> FFN -> LN2 -> mask (in-place on d_out) ----------------
__global__ __launch_bounds__(256,2) void ffn_kernel(
    const float* __restrict__ ln1g, const float* __restrict__ ln1b,
    const short* __restrict__ winT, const float* __restrict__ bin,
    const short* __restrict__ woutT, const float* __restrict__ bout,
    const float* __restrict__ ln2g, const float* __restrict__ ln2b,
    const float* __restrict__ maskV, float* __restrict__ io)
{
  const int row0 = blockIdx.x * 32;
  const int tid = threadIdx.x, lane = tid & 63, wv = tid >> 6;
  __shared__ __attribute__((aligned(16))) short Xs[32][Hh + 8];
  __shared__ __attribute__((aligned(16))) float Rs[32][Hh + 4];
  __shared__ __attribute__((aligned(16))) short Hs[32][FFd + 8];

  const int arow = lane & 15, kgrp = (lane >> 4) * 8;
  const int ccol = lane & 15, crow0 = (lane >> 4) * 4;

  {
    int r = tid >> 3, cb = (tid & 7) * 16;
    const float4* xp = (const float4*)(io + (size_t)(row0 + r)*Hh + cb);
    float xv[16];
    #pragma unroll
    for (int j = 0; j < 4; ++j){
      float4 v = xp[j];
      xv[j*4+0]=v.x; xv[j*4+1]=v.y; xv[j*4+2]=v.z; xv[j*4+3]=v.w;
    }
    float sum = 0.f, sq = 0.f;
    #pragma unroll
    for (int j = 0; j < 16; ++j){ sum += xv[j]; sq += xv[j]*xv[j]; }
    #pragma unroll
    for (int d = 1; d < 8; d <<= 1){ sum += __shfl_xor(sum, d); sq += __shfl_xor(sq, d); }
    float mu = sum * (1.0f/128.0f);
    float var = sq * (1.0f/128.0f) - mu*mu;
    float rstd = rsqrtf(var + 1e-5f);
    #pragma unroll
    for (int j = 0; j < 16; ++j){
      int c = cb + j;
      float xn = (xv[j] - mu) * rstd * ln1g[c] + ln1b[c];
      Xs[r][c] = f2bf1(xn);
      Rs[r][c] = xn;
    }
  }
  __syncthreads();

  {
    f32x4 acc[2][8];
    #pragma unroll
    for (int m = 0; m < 2; ++m) for (int n = 0; n < 8; ++n) acc[m][n] = (f32x4){0.f,0.f,0.f,0.f};
    const short8v* Bw = (const short8v*)winT;
    #pragma unroll
    for (int ks = 0; ks < 4; ++ks){
      int kb = ks*32 + kgrp;
      short8v a0 = *(const short8v*)&Xs[arow][kb];
      short8v a1 = *(const short8v*)&Xs[16 + arow][kb];
      #pragma unroll
      for (int n = 0; n < 8; ++n){
        short8v b = Bw[(wv*128 + n*16 + arow)*16 + (kb >> 3)];
        acc[0][n] = __builtin_amdgcn_mfma_f32_16x16x32_bf16(a0,b,acc[0][n],0,0,0);
        acc[1][n] = __builtin_amdgcn_mfma_f32_16x16x32_bf16(a1,b,acc[1][n],0,0,0);
      }
    }
    #pragma unroll
    for (int m = 0; m < 2; ++m) for (int n = 0; n < 8; ++n){
      int colg = wv*128 + n*16 + ccol;
      float bb = bin[colg];
      #pragma unroll
      for (int r = 0; r < 4; ++r)
        Hs[m*16 + crow0 + r][colg] = f2bf1(gelu_f(acc[m][n][r] + bb));
    }
  }
  __syncthreads();

  {
    f32x4 acc[2][2];
    #pragma unroll
    for (int m = 0; m < 2; ++m) for (int n = 0; n < 2; ++n) acc[m][n] = (f32x4){0.f,0.f,0.f,0.f};
    const short8v* Bw = (const short8v*)woutT;
    #pragma unroll
    for (int ks = 0; ks < 16; ++ks){
      int kb = ks*32 + kgrp;
      short8v a0 = *(const short8v*)&Hs[arow][kb];
      short8v a1 = *(const short8v*)&Hs[16 + arow][kb];
      short8v b0 = Bw[(wv*32 + arow)*64      + (kb >> 3)];
      short8v b1f = Bw[(wv*32 + 16 + arow)*64 + (kb >> 3)];
      acc[0][0] = __builtin_amdgcn_mfma_f32_16x16x32_bf16(a0,b0, acc[0][0],0,0,0);
      acc[1][0] = __builtin_amdgcn_mfma_f32_16x16x32_bf16(a1,b0, acc[1][0],0,0,0);
      acc[0][1] = __builtin_amdgcn_mfma_f32_16x16x32_bf16(a0,b1f,acc[0][1],0,0,0);
      acc[1][1] = __builtin_amdgcn_mfma_f32_16x16x32_bf16(a1,b1f,acc[1][1],0,0,0);
    }
    #pragma unroll
    for (int m = 0; m < 2; ++m) for (int n = 0; n < 2; ++n){
      int colg = wv*32 + n*16 + ccol;
      float bb = bout[colg];
      #pragma unroll
      for (int r = 0; r < 4; ++r){
        int rr = m*16 + crow0 + r;
        Rs[rr][colg] = Rs[rr][colg] + acc[m][n][r] + bb;
      }
    }
  }
  __syncthreads();

  {
    int r = tid >> 3, cb = (tid & 7) * 16;
    float xv[16];
    #pragma unroll
    for (int j = 0; j < 16; ++j) xv[j] = Rs[r][cb + j];
    float sum = 0.f, sq = 0.f;
    #pragma unroll
    for (int j = 0; j < 16; ++j){ sum += xv[j]; sq += xv[j]*xv[j]; }
    #pragma unroll
    for (int d = 1; d < 8; d <<= 1){ sum += __shfl_xor(sum, d); sq += __shfl_xor(sq, d); }
    float mu = sum * (1.0f/128.0f);
    float var = sq * (1.0f/128.0f) - mu*mu;
    float rstd = rsqrtf(var + 1e-5f);
    float mv = maskV[row0 + r];
    float* op = io + (size_t)(row0 + r)*Hh + cb;
    #pragma unroll
    for (int j = 0; j < 4; ++j){
      float4 o;
      o.x = ((xv[j*4+0] - mu)*rstd*ln2g[cb+j*4+0] + ln2b[cb+j*4+0]) * mv;
      o.y = ((xv[j*4+1] - mu)*rstd*ln2g[cb+j*4+1] + ln2b[cb+j*4+1]) * mv;
      o.z = ((xv[j*4+2] - mu)*rstd*ln2g[cb+j*4+2] + ln2b[cb+j*4+2]) * mv;
      o.w = ((xv[j*4+3] - mu)*rstd*ln2g[cb+j*4+3] + ln2b[cb+j*4+3]) * mv;
      ((float4*)op)[j] = o;
    }
  }
}

extern "C" void kernel_launch(void* const* d_in, const int* in_sizes, int n_in,
                              void* d_out, int out_size, void* d_ws, size_t ws_size,
                              hipStream_t stream)
{
  const float* hV    = (const float*)d_in[0];
  const float* hE    = (const float*)d_in[1];
  const float* maskV = (const float*)d_in[2];
  const float* maskA = (const float*)d_in[3];
  const float* W1w   = (const float*)d_in[4];
  const float* W1b   = (const float*)d_in[5];
  const float* W2w   = (const float*)d_in[6];
  const float* W2b   = (const float*)d_in[7];
  const float* W3w   = (const float*)d_in[8];
  const float* W3b   = (const float*)d_in[9];
  const float* Winw  = (const float*)d_in[10];
  const float* Winb  = (const float*)d_in[11];
  const float* Woutw = (const float*)d_in[12];
  const float* Woutb = (const float*)d_in[13];
  const float* l1g   = (const float*)d_in[14];
  const float* l1b   = (const float*)d_in[15];
  const float* l2g   = (const float*)d_in[16];
  const float* l2b   = (const float*)d_in[17];

  char* ws = (char*)d_ws;
  size_t off = 0;
  float* npart = (float*)(ws + off); off += (size_t)NNODE * Hh * 4;
  short* w1vT  = (short*)(ws + off); off += 16384*2;
  short* w1p   = (short*)(ws + off); off += 49152*2;
  short* w2p   = (short*)(ws + off); off += 16384*2;
  short* w3p   = (short*)(ws + off); off += 16384*2;
  short* winT  = (short*)(ws + off); off += 65536*2;
  short* woutT = (short*)(ws + off); off += 65536*2;
  if (ws_size < off) return;

  prep_weights<<<896, 256, 0, stream>>>(W1w, W2w, W3w, Winw, Woutw,
                                        w1vT, w1p, w2p, w3p, winT, woutT);
  np_kernel<<<NNODE/32, 256, 0, stream>>>(hV, w1vT, W1b, npart);
  edge_kernel<<<EGRID, 512, 0, stream>>>(hE, hV, maskA, npart,
                                         w1p, w2p, w3p, W2b, W3b, (float*)d_out);
  ffn_kernel<<<NNODE/32, 256, 0, stream>>>(l1g, l1b, winT, Winb, woutT, Woutb,
                                           l2g, l2b, maskV, (float*)d_out);
}

// Round 11
// 236.258 us; speedup vs baseline: 1.6032x; 1.6032x over previous
//
#include <hip/hip_runtime.h>
#include <hip/hip_bf16.h>

#define Hh    128
#define NINc  384
#define KN    48
#define FFd   512
#define NNODE 8192

typedef __attribute__((ext_vector_type(8))) short short8v;
typedef __attribute__((ext_vector_type(4))) float f32x4;

__device__ __forceinline__ short f2bf1(float f){
  union { __hip_bfloat16 h; short s; } c; c.h = __float2bfloat16(f);
  return c.s;
}
__device__ __forceinline__ unsigned pk_bf16(float lo, float hi){
  union { __hip_bfloat162 h; unsigned u; } c;
  c.h = __float22bfloat162_rn(make_float2(lo, hi));
  return c.u;
}
// 8 consecutive f32 -> bf16x8 fragment
__device__ __forceinline__ short8v pack8(float4 a, float4 b){
  union { short8v s; unsigned u[4]; } r;
  r.u[0] = pk_bf16(a.x, a.y); r.u[1] = pk_bf16(a.z, a.w);
  r.u[2] = pk_bf16(b.x, b.y); r.u[3] = pk_bf16(b.z, b.w);
  return r.s;
}

// 0.5x(1+tanh(t)) == x*sigmoid(2t); max dev from erf-GELU ~3e-4
__device__ __forceinline__ float gelu_f(float x){
  float t = 0.7978845608028654f * x * (1.0f + 0.044715f * x * x);
  float e = __expf(2.0f * t);
  return x * (1.0f - 1.0f / (e + 1.0f));
}

// LDS-publish barrier WITHOUT vmem drain
__device__ __forceinline__ void bar_lds(){
  asm volatile("s_waitcnt lgkmcnt(0)\n\ts_barrier" ::: "memory");
}

// ---------------- weight prep ----------------
// w1vT: [128 out][128 in] (np_kernel). w1p/w2p/w3p fragment-packed:
// [ntile][ks][lane][8] bf16 -> one wave frag = 1 contiguous KB.
__global__ void prep_weights(const float* __restrict__ W1, const float* __restrict__ W2,
                             const float* __restrict__ W3, const float* __restrict__ Win,
                             const float* __restrict__ Wout,
                             short* __restrict__ w1vT, short* __restrict__ w1p,
                             short* __restrict__ w2p,  short* __restrict__ w3p,
                             short* __restrict__ winT, short* __restrict__ woutT)
{
  int i = blockIdx.x * 256 + threadIdx.x;
  if (i < 16384){ int n = i / 128, k = i % 128; w1vT[i] = f2bf1(W1[k*128 + n]); return; }
  i -= 16384;
  if (i < 49152){ // w1p: n<8, ks<12
    int n = i / 6144, r = i % 6144;
    int ks = r / 512, r2 = r % 512;
    int lane = r2 / 8, j = r2 % 8;
    int qq = lane >> 4, arow = lane & 15;
    w1p[i] = f2bf1(W1[(128 + ks*32 + qq*8 + j)*128 + n*16 + arow]); return;
  }
  i -= 49152;
  if (i < 16384){ // w2p: n<8, ks<4
    int n = i / 2048, r = i % 2048;
    int ks = r / 512, r2 = r % 512;
    int lane = r2 / 8, j = r2 % 8;
    int qq = lane >> 4, arow = lane & 15;
    w2p[i] = f2bf1(W2[(ks*32 + qq*8 + j)*128 + n*16 + arow]); return;
  }
  i -= 16384;
  if (i < 16384){ // w3p
    int n = i / 2048, r = i % 2048;
    int ks = r / 512, r2 = r % 512;
    int lane = r2 / 8, j = r2 % 8;
    int qq = lane >> 4, arow = lane & 15;
    w3p[i] = f2bf1(W3[(ks*32 + qq*8 + j)*128 + n*16 + arow]); return;
  }
  i -= 16384;
  if (i < 65536){ int n = i / 128, k = i % 128; winT[i] = f2bf1(Win[k*512 + n]); return; }
  i -= 65536;
  if (i < 65536){ int n = i / 512, k = i % 512; woutT[i] = f2bf1(Wout[k*128 + n]); return; }
}

// ---------------- node_part = h_V @ W1[:128,:] + b1  (256 blocks, 32 rows) ----
__global__ __launch_bounds__(256,4) void np_kernel(
    const float* __restrict__ hV, const short* __restrict__ w1vT,
    const float* __restrict__ b1, float* __restrict__ npart)
{
  const int row0 = blockIdx.x * 32;
  const int tid = threadIdx.x, lane = tid & 63, wv = tid >> 6;
  __shared__ __attribute__((aligned(16))) short Xs[32][Hh + 8];

  const float4* src = (const float4*)(hV + (size_t)row0 * Hh);
  #pragma unroll
  for (int j = 0; j < 4; ++j){
    int idx = tid + 256*j;
    int r = idx >> 5, c4 = idx & 31;
    float4 v = src[idx];
    *(uint2*)&Xs[r][c4*4] = make_uint2(pk_bf16(v.x,v.y), pk_bf16(v.z,v.w));
  }
  __syncthreads();

  const int arow = lane & 15, kgrp = (lane >> 4) * 8;
  const int col0 = wv * 32, ccol = lane & 15, crow0 = (lane >> 4) * 4;

  f32x4 acc[2][2];
  #pragma unroll
  for (int m = 0; m < 2; ++m) for (int n = 0; n < 2; ++n) acc[m][n] = (f32x4){0.f,0.f,0.f,0.f};

  const short8v* Bw = (const short8v*)w1vT;
  #pragma unroll
  for (int ks = 0; ks < 4; ++ks){
    int kb = ks*32 + kgrp;
    short8v b0 = Bw[(col0 + arow)*16      + (kb >> 3)];
    short8v b1f = Bw[(col0 + 16 + arow)*16 + (kb >> 3)];
    #pragma unroll
    for (int m = 0; m < 2; ++m){
      short8v a = *(const short8v*)&Xs[m*16 + arow][kb];
      acc[m][0] = __builtin_amdgcn_mfma_f32_16x16x32_bf16(a, b0,  acc[m][0], 0,0,0);
      acc[m][1] = __builtin_amdgcn_mfma_f32_16x16x32_bf16(a, b1f, acc[m][1], 0,0,0);
    }
  }
  #pragma unroll
  for (int m = 0; m < 2; ++m) for (int n = 0; n < 2; ++n){
    int colg = col0 + n*16 + ccol;
    float bb = b1[colg];
    #pragma unroll
    for (int r = 0; r < 4; ++r)
      npart[(size_t)(row0 + m*16 + crow0 + r)*Hh + colg] = acc[m][n][r] + bb;
  }
}

// ---------------- edge MLP: global_load_lds staging, swapped-operand MFMA ----
// One node per 4-wave block. Staging = 72 x 1KB async global_load_lds chunks
// (fp32, LINEAR LDS dest) with SOURCE-side 16B-slot XOR swizzle (gs = sp^(r&7));
// G1 reads apply the same XOR -> uniform 8 lanes/bank-group (conflict-free).
// Zero staging VALU / zero staging VGPRs; the single vmcnt drain at
// __syncthreads IS the true dependency. M1/M2 (bf16) alias Etf after G1's
// read-fence. LDS 73.7KB -> 2 blocks/CU.
__global__ __launch_bounds__(256,2) void edge_kernel(
    const float* __restrict__ hE, const float* __restrict__ hV,
    const float* __restrict__ maskA, const float* __restrict__ npart,
    const short* __restrict__ w1p, const short* __restrict__ w2p,
    const short* __restrict__ w3p,
    const float* __restrict__ b2, const float* __restrict__ b3,
    float* __restrict__ out)
{
  const int node = blockIdx.x;
  const int tid = threadIdx.x, lane = tid & 63, wv = tid >> 6;   // wv 0..3
  const int e = lane & 15, q = lane >> 4;
  const int n0 = wv * 32;

  __shared__ __attribute__((aligned(16))) float Etf[KN * NINc];  // 73728B linear
  short (*M1)[136] = (short (*)[136])&Etf[0];
  short (*M2)[136] = (short (*)[136])((short*)&Etf[0] + KN*136);

  // ---- async stage: each wave issues 18 x 1KB global_load_lds (16B/lane) ----
  {
    const char* gb = (const char*)(hE + (size_t)node * (KN*NINc));
    #pragma unroll
    for (int j = 0; j < 18; ++j){
      int chunk = wv*18 + j;            // 0..71, wave-uniform
      int S = chunk*64 + lane;          // this lane's linear LDS 16B-slot
      int r = S / 96, sp = S - r*96;    // row, in-row slot (96 slots/row)
      int gs = sp ^ (r & 7);            // source-side swizzle (involution)
      __builtin_amdgcn_global_load_lds(
        (const __attribute__((address_space(1))) unsigned int*)
            (gb + ((size_t)r*96 + gs)*16),
        (__attribute__((address_space(3))) unsigned int*)
            ((char*)&Etf[0] + chunk*1024),
        16, 0, 0);
    }
  }

  // invariants needed by G1 epilogue / G3 (drained by the same syncthreads)
  const float4 npv0 = *(const float4*)(npart + (size_t)node*Hh + n0 + 4*q);
  const float4 npv1 = *(const float4*)(npart + (size_t)node*Hh + n0 + 16 + 4*q);
  const float mk0 = maskA[node*KN + e];
  const float mk1 = maskA[node*KN + 16 + e];
  const float mk2 = maskA[node*KN + 32 + e];

  __syncthreads();   // vmcnt(0) drain = the true data dependency (Etf ready)

  const f32x4 Z = (f32x4){0.f,0.f,0.f,0.f};

  #define WR_M(DST, ACC, ET, COLB, BV)  { short4 s;                 \
    s.x = f2bf1(gelu_f(ACC[0] + BV.x));                             \
    s.y = f2bf1(gelu_f(ACC[1] + BV.y));                             \
    s.z = f2bf1(gelu_f(ACC[2] + BV.z));                             \
    s.w = f2bf1(gelu_f(ACC[3] + BV.w));                             \
    *(short4*)&DST[16*ET + e][COLB + 4*q] = s; }

  // fragment read: row, base slot s0 (even); same XOR as stage side
  #define RD_F(ROW, S0)  pack8(                                     \
      *(const float4*)&Etf[(ROW)*384 + (((S0)  ) ^ ((ROW)&7))*4],   \
      *(const float4*)&Etf[(ROW)*384 + (((S0)+1) ^ ((ROW)&7))*4])

  // ---- G1: (Et·W1e)^T via mfma(w1 frags, swizzle-read f32 frags) ----
  f32x4 a00=Z, a10=Z, a20=Z, a01=Z, a11=Z, a21=Z;
  {
    const short8v* B1 = (const short8v*)w1p;
    #pragma unroll
    for (int ks = 0; ks < 12; ++ks){
      short8v f0 = B1[((2*wv  )*12 + ks)*64 + lane];
      short8v f1 = B1[((2*wv+1)*12 + ks)*64 + lane];
      int s0 = ks*8 + q*2;
      short8v t0 = RD_F(e,      s0);
      short8v t1 = RD_F(16 + e, s0);
      short8v t2 = RD_F(32 + e, s0);
      a00 = __builtin_amdgcn_mfma_f32_16x16x32_bf16(f0, t0, a00, 0,0,0);
      a10 = __builtin_amdgcn_mfma_f32_16x16x32_bf16(f0, t1, a10, 0,0,0);
      a20 = __builtin_amdgcn_mfma_f32_16x16x32_bf16(f0, t2, a20, 0,0,0);
      a01 = __builtin_amdgcn_mfma_f32_16x16x32_bf16(f1, t0, a01, 0,0,0);
      a11 = __builtin_amdgcn_mfma_f32_16x16x32_bf16(f1, t1, a11, 0,0,0);
      a21 = __builtin_amdgcn_mfma_f32_16x16x32_bf16(f1, t2, a21, 0,0,0);
    }
  }
  bar_lds();   // READ-FENCE: all waves done reading Etf -> alias region reusable

  // b2 loads issued here, in flight under the M1 write + barrier
  const float4 b2v0 = *(const float4*)(b2 + n0 + 4*q);
  const float4 b2v1 = *(const float4*)(b2 + n0 + 16 + 4*q);

  {
    WR_M(M1, a00, 0, n0,      npv0)  WR_M(M1, a10, 1, n0,      npv0)
    WR_M(M1, a20, 2, n0,      npv0)  WR_M(M1, a01, 0, n0 + 16, npv1)
    WR_M(M1, a11, 1, n0 + 16, npv1)  WR_M(M1, a21, 2, n0 + 16, npv1)
  }
  bar_lds();   // M1 visible

  // ---- G2: (M1·W2)^T -> gelu(+b2) -> M2 (disjoint alias region) ----
  {
    f32x4 c00=Z, c10=Z, c20=Z, c01=Z, c11=Z, c21=Z;
    const short8v* B2f = (const short8v*)w2p;
    #pragma unroll
    for (int ks = 0; ks < 4; ++ks){
      short8v f0 = B2f[((2*wv  )*4 + ks)*64 + lane];
      short8v f1 = B2f[((2*wv+1)*4 + ks)*64 + lane];
      int kb = ks*32 + q*8;
      short8v t0 = *(const short8v*)&M1[e][kb];
      short8v t1 = *(const short8v*)&M1[16 + e][kb];
      short8v t2 = *(const short8v*)&M1[32 + e][kb];
      c00 = __builtin_amdgcn_mfma_f32_16x16x32_bf16(f0, t0, c00, 0,0,0);
      c10 = __builtin_amdgcn_mfma_f32_16x16x32_bf16(f0, t1, c10, 0,0,0);
      c20 = __builtin_amdgcn_mfma_f32_16x16x32_bf16(f0, t2, c20, 0,0,0);
      c01 = __builtin_amdgcn_mfma_f32_16x16x32_bf16(f1, t0, c01, 0,0,0);
      c11 = __builtin_amdgcn_mfma_f32_16x16x32_bf16(f1, t1, c11, 0,0,0);
      c21 = __builtin_amdgcn_mfma_f32_16x16x32_bf16(f1, t2, c21, 0,0,0);
    }
    WR_M(M2, c00, 0, n0,      b2v0)  WR_M(M2, c10, 1, n0,      b2v0)
    WR_M(M2, c20, 2, n0,      b2v0)  WR_M(M2, c01, 0, n0 + 16, b2v1)
    WR_M(M2, c11, 1, n0 + 16, b2v1)  WR_M(M2, c21, 2, n0 + 16, b2v1)
  }

  // b3/hV loads issued here, in flight under the barrier + G3 loop
  const float4 b3v0 = *(const float4*)(b3 + n0 + 4*q);
  const float4 b3v1 = *(const float4*)(b3 + n0 + 16 + 4*q);
  const float4 hvv0 = *(const float4*)(hV + (size_t)node*Hh + n0 + 4*q);
  const float4 hvv1 = *(const float4*)(hV + (size_t)node*Hh + n0 + 16 + 4*q);

  bar_lds();   // M2 visible

  // ---- G3: (M2·W3)^T -> masked shfl-butterfly sum over edges -> out ----
  {
    f32x4 d00=Z, d10=Z, d20=Z, d01=Z, d11=Z, d21=Z;
    const short8v* B3f = (const short8v*)w3p;
    #pragma unroll
    for (int ks = 0; ks < 4; ++ks){
      short8v f0 = B3f[((2*wv  )*4 + ks)*64 + lane];
      short8v f1 = B3f[((2*wv+1)*4 + ks)*64 + lane];
      int kb = ks*32 + q*8;
      short8v t0 = *(const short8v*)&M2[e][kb];
      short8v t1 = *(const short8v*)&M2[16 + e][kb];
      short8v t2 = *(const short8v*)&M2[32 + e][kb];
      d00 = __builtin_amdgcn_mfma_f32_16x16x32_bf16(f0, t0, d00, 0,0,0);
      d10 = __builtin_amdgcn_mfma_f32_16x16x32_bf16(f0, t1, d10, 0,0,0);
      d20 = __builtin_amdgcn_mfma_f32_16x16x32_bf16(f0, t2, d20, 0,0,0);
      d01 = __builtin_amdgcn_mfma_f32_16x16x32_bf16(f1, t0, d01, 0,0,0);
      d11 = __builtin_amdgcn_mfma_f32_16x16x32_bf16(f1, t1, d11, 0,0,0);
      d21 = __builtin_amdgcn_mfma_f32_16x16x32_bf16(f1, t2, d21, 0,0,0);
    }
    f32x4 v0, v1;
    #pragma unroll
    for (int r = 0; r < 4; ++r){
      v0[r] = (d00[r] + b3v0[r])*mk0 + (d10[r] + b3v0[r])*mk1 + (d20[r] + b3v0[r])*mk2;
      v1[r] = (d01[r] + b3v1[r])*mk0 + (d11[r] + b3v1[r])*mk1 + (d21[r] + b3v1[r])*mk2;
    }
    #pragma unroll
    for (int s = 1; s <= 8; s <<= 1){
      #pragma unroll
      for (int r = 0; r < 4; ++r){
        v0[r] += __shfl_xor(v0[r], s);
        v1[r] += __shfl_xor(v1[r], s);
      }
    }
    if (e == 0){
      float4 o0, o1;
      o0.x = hvv0.x + v0[0]*(1.0f/30.0f); o0.y = hvv0.y + v0[1]*(1.0f/30.0f);
      o0.z = hvv0.z + v0[2]*(1.0f/30.0f); o0.w = hvv0.w + v0[3]*(1.0f/30.0f);
      o1.x = hvv1.x + v1[0]*(1.0f/30.0f); o1.y = hvv1.y + v1[1]*(1.0f/30.0f);
      o1.z = hvv1.z + v1[2]*(1.0f/30.0f); o1.w = hvv1.w + v1[3]*(1.0f/30.0f);
      *(float4*)(out + (size_t)node*Hh + n0 + 4*q)      = o0;
      *(float4*)(out + (size_t)node*Hh + n0 + 16 + 4*q) = o1;
    }
  }
  #undef WR_M
  #undef RD_F
}

// ---------------- batched LN1 -> FFN -> LN2 -> mask (in-place on d_out) ----------------
__global__ __launch_bounds__(256,2) void ffn_kernel(
    const float* __restrict__ ln1g, const float* __restrict__ ln1b,
    const short* __restrict__ winT, const float* __restrict__ bin,
    const short* __restrict__ woutT, const float* __restrict__ bout,
    const float* __restrict__ ln2g, const float* __restrict__ ln2b,
    const float* __restrict__ maskV, float* __restrict__ io)
{
  const int row0 = blockIdx.x * 32;
  const int tid = threadIdx.x, lane = tid & 63, wv = tid >> 6;
  __shared__ __attribute__((aligned(16))) short Xs[32][Hh + 8];
  __shared__ __attribute__((aligned(16))) float Rs[32][Hh + 4];
  __shared__ __attribute__((aligned(16))) short Hs[32][FFd + 8];

  const int arow = lane & 15, kgrp = (lane >> 4) * 8;
  const int ccol = lane & 15, crow0 = (lane >> 4) * 4;

  {
    int r = tid >> 3, cb = (tid & 7) * 16;
    const float4* xp = (const float4*)(io + (size_t)(row0 + r)*Hh + cb);
    float xv[16];
    #pragma unroll
    for (int j = 0; j < 4; ++j){
      float4 v = xp[j];
      xv[j*4+0]=v.x; xv[j*4+1]=v.y; xv[j*4+2]=v.z; xv[j*4+3]=v.w;
    }
    float sum = 0.f, sq = 0.f;
    #pragma unroll
    for (int j = 0; j < 16; ++j){ sum += xv[j]; sq += xv[j]*xv[j]; }
    #pragma unroll
    for (int d = 1; d < 8; d <<= 1){ sum += __shfl_xor(sum, d); sq += __shfl_xor(sq, d); }
    float mu = sum * (1.0f/128.0f);
    float var = sq * (1.0f/128.0f) - mu*mu;
    float rstd = rsqrtf(var + 1e-5f);
    #pragma unroll
    for (int j = 0; j < 16; ++j){
      int c = cb + j;
      float xn = (xv[j] - mu) * rstd * ln1g[c] + ln1b[c];
      Xs[r][c] = f2bf1(xn);
      Rs[r][c] = xn;
    }
  }
  __syncthreads();

  {
    f32x4 acc[2][8];
    #pragma unroll
    for (int m = 0; m < 2; ++m) for (int n = 0; n < 8; ++n) acc[m][n] = (f32x4){0.f,0.f,0.f,0.f};
    const short8v* Bw = (const short8v*)winT;
    #pragma unroll
    for (int ks = 0; ks < 4; ++ks){
      int kb = ks*32 + kgrp;
      short8v a0 = *(const short8v*)&Xs[arow][kb];
      short8v a1 = *(const short8v*)&Xs[16 + arow][kb];
      #pragma unroll
      for (int n = 0; n < 8; ++n){
        short8v b = Bw[(wv*128 + n*16 + arow)*16 + (kb >> 3)];
        acc[0][n] = __builtin_amdgcn_mfma_f32_16x16x32_bf16(a0,b,acc[0][n],0,0,0);
        acc[1][n] = __builtin_amdgcn_mfma_f32_16x16x32_bf16(a1,b,acc[1][n],0,0,0);
      }
    }
    #pragma unroll
    for (int m = 0; m < 2; ++m) for (int n = 0; n < 8; ++n){
      int colg = wv*128 + n*16 + ccol;
      float bb = bin[colg];
      #pragma unroll
      for (int r = 0; r < 4; ++r)
        Hs[m*16 + crow0 + r][colg] = f2bf1(gelu_f(acc[m][n][r] + bb));
    }
  }
  __syncthreads();

  {
    f32x4 acc[2][2];
    #pragma unroll
    for (int m = 0; m < 2; ++m) for (int n = 0; n < 2; ++n) acc[m][n] = (f32x4){0.f,0.f,0.f,0.f};
    const short8v* Bw = (const short8v*)woutT;
    #pragma unroll
    for (int ks = 0; ks < 16; ++ks){
      int kb = ks*32 + kgrp;
      short8v a0 = *(const short8v*)&Hs[arow][kb];
      short8v a1 = *(const short8v*)&Hs[16 + arow][kb];
      short8v b0 = Bw[(wv*32 + arow)*64      + (kb >> 3)];
      short8v b1f = Bw[(wv*32 + 16 + arow)*64 + (kb >> 3)];
      acc[0][0] = __builtin_amdgcn_mfma_f32_16x16x32_bf16(a0,b0, acc[0][0],0,0,0);
      acc[1][0] = __builtin_amdgcn_mfma_f32_16x16x32_bf16(a1,b0, acc[1][0],0,0,0);
      acc[0][1] = __builtin_amdgcn_mfma_f32_16x16x32_bf16(a0,b1f,acc[0][1],0,0,0);
      acc[1][1] = __builtin_amdgcn_mfma_f32_16x16x32_bf16(a1,b1f,acc[1][1],0,0,0);
    }
    #pragma unroll
    for (int m = 0; m < 2; ++m) for (int n = 0; n < 2; ++n){
      int colg = wv*32 + n*16 + ccol;
      float bb = bout[colg];
      #pragma unroll
      for (int r = 0; r < 4; ++r){
        int rr = m*16 + crow0 + r;
        Rs[rr][colg] = Rs[rr][colg] + acc[m][n][r] + bb;
      }
    }
  }
  __syncthreads();

  {
    int r = tid >> 3, cb = (tid & 7) * 16;
    float xv[16];
    #pragma unroll
    for (int j = 0; j < 16; ++j) xv[j] = Rs[r][cb + j];
    float sum = 0.f, sq = 0.f;
    #pragma unroll
    for (int j = 0; j < 16; ++j){ sum += xv[j]; sq += xv[j]*xv[j]; }
    #pragma unroll
    for (int d = 1; d < 8; d <<= 1){ sum += __shfl_xor(sum, d); sq += __shfl_xor(sq, d); }
    float mu = sum * (1.0f/128.0f);
    float var = sq * (1.0f/128.0f) - mu*mu;
    float rstd = rsqrtf(var + 1e-5f);
    float mv = maskV[row0 + r];
    float* op = io + (size_t)(row0 + r)*Hh + cb;
    #pragma unroll
    for (int j = 0; j < 4; ++j){
      float4 o;
      o.x = ((xv[j*4+0] - mu)*rstd*ln2g[cb+j*4+0] + ln2b[cb+j*4+0]) * mv;
      o.y = ((xv[j*4+1] - mu)*rstd*ln2g[cb+j*4+1] + ln2b[cb+j*4+1]) * mv;
      o.z = ((xv[j*4+2] - mu)*rstd*ln2g[cb+j*4+2] + ln2b[cb+j*4+2]) * mv;
      o.w = ((xv[j*4+3] - mu)*rstd*ln2g[cb+j*4+3] + ln2b[cb+j*4+3]) * mv;
      ((float4*)op)[j] = o;
    }
  }
}

extern "C" void kernel_launch(void* const* d_in, const int* in_sizes, int n_in,
                              void* d_out, int out_size, void* d_ws, size_t ws_size,
                              hipStream_t stream)
{
  const float* hV    = (const float*)d_in[0];
  const float* hE    = (const float*)d_in[1];
  const float* maskV = (const float*)d_in[2];
  const float* maskA = (const float*)d_in[3];
  const float* W1w   = (const float*)d_in[4];
  const float* W1b   = (const float*)d_in[5];
  const float* W2w   = (const float*)d_in[6];
  const float* W2b   = (const float*)d_in[7];
  const float* W3w   = (const float*)d_in[8];
  const float* W3b   = (const float*)d_in[9];
  const float* Winw  = (const float*)d_in[10];
  const float* Winb  = (const float*)d_in[11];
  const float* Woutw = (const float*)d_in[12];
  const float* Woutb = (const float*)d_in[13];
  const float* l1g   = (const float*)d_in[14];
  const float* l1b   = (const float*)d_in[15];
  const float* l2g   = (const float*)d_in[16];
  const float* l2b   = (const float*)d_in[17];

  char* ws = (char*)d_ws;
  size_t off = 0;
  float* npart = (float*)(ws + off); off += (size_t)NNODE * Hh * 4;
  short* w1vT  = (short*)(ws + off); off += 16384*2;
  short* w1p   = (short*)(ws + off); off += 49152*2;
  short* w2p   = (short*)(ws + off); off += 16384*2;
  short* w3p   = (short*)(ws + off); off += 16384*2;
  short* winT  = (short*)(ws + off); off += 65536*2;
  short* woutT = (short*)(ws + off); off += 65536*2;
  if (ws_size < off) return;

  prep_weights<<<896, 256, 0, stream>>>(W1w, W2w, W3w, Winw, Woutw,
                                        w1vT, w1p, w2p, w3p, winT, woutT);
  np_kernel<<<NNODE/32, 256, 0, stream>>>(hV, w1vT, W1b, npart);
  edge_kernel<<<NNODE, 256, 0, stream>>>(hE, hV, maskA, npart,
                                         w1p, w2p, w3p, W2b, W3b, (float*)d_out);
  ffn_kernel<<<NNODE/32, 256, 0, stream>>>(l1g, l1b, winT, Winb, woutT, Woutb,
                                           l2g, l2b, maskV, (float*)d_out);
}

// Round 12
// 191.969 us; speedup vs baseline: 1.9730x; 1.2307x over previous
//
#include <hip/hip_runtime.h>
#include <hip/hip_bf16.h>

#define Hh    128
#define NINc  384
#define KN    48
#define FFd   512
#define NNODE 8192

typedef __attribute__((ext_vector_type(8))) short short8v;
typedef __attribute__((ext_vector_type(4))) float f32x4;

__device__ __forceinline__ short f2bf1(float f){
  union { __hip_bfloat16 h; short s; } c; c.h = __float2bfloat16(f);
  return c.s;
}
__device__ __forceinline__ unsigned pk_bf16(float lo, float hi){
  union { __hip_bfloat162 h; unsigned u; } c;
  c.h = __float22bfloat162_rn(make_float2(lo, hi));
  return c.u;
}

// 0.5x(1+tanh(t)) == x*sigmoid(2t); max dev from erf-GELU ~3e-4
__device__ __forceinline__ float gelu_f(float x){
  float t = 0.7978845608028654f * x * (1.0f + 0.044715f * x * x);
  float e = __expf(2.0f * t);
  return x * (1.0f - 1.0f / (e + 1.0f));
}

// LDS-publish barrier WITHOUT vmem drain (prefetch loads stay in flight)
__device__ __forceinline__ void bar_lds(){
  asm volatile("s_waitcnt lgkmcnt(0)\n\ts_barrier" ::: "memory");
}

// ---------------- weight prep ----------------
// w1vT/w3T: [128 out][128 in] bf16. w1p/w2p fragment-packed:
// [ntile][ks][lane][8] bf16 -> one wave frag = 1 contiguous KB.
__global__ void prep_weights(const float* __restrict__ W1, const float* __restrict__ W2,
                             const float* __restrict__ W3, const float* __restrict__ Win,
                             const float* __restrict__ Wout,
                             short* __restrict__ w1vT, short* __restrict__ w1p,
                             short* __restrict__ w2p,  short* __restrict__ w3T,
                             short* __restrict__ winT, short* __restrict__ woutT)
{
  int i = blockIdx.x * 256 + threadIdx.x;
  if (i < 16384){ int n = i / 128, k = i % 128; w1vT[i] = f2bf1(W1[k*128 + n]); return; }
  i -= 16384;
  if (i < 49152){ // w1p: n<8, ks<12
    int n = i / 6144, r = i % 6144;
    int ks = r / 512, r2 = r % 512;
    int lane = r2 / 8, j = r2 % 8;
    int qq = lane >> 4, arow = lane & 15;
    w1p[i] = f2bf1(W1[(128 + ks*32 + qq*8 + j)*128 + n*16 + arow]); return;
  }
  i -= 49152;
  if (i < 16384){ // w2p: n<8, ks<4
    int n = i / 2048, r = i % 2048;
    int ks = r / 512, r2 = r % 512;
    int lane = r2 / 8, j = r2 % 8;
    int qq = lane >> 4, arow = lane & 15;
    w2p[i] = f2bf1(W2[(ks*32 + qq*8 + j)*128 + n*16 + arow]); return;
  }
  i -= 16384;
  if (i < 16384){ int n = i / 128, k = i % 128; w3T[i] = f2bf1(W3[k*128 + n]); return; }
  i -= 16384;
  if (i < 65536){ int n = i / 128, k = i % 128; winT[i] = f2bf1(Win[k*512 + n]); return; }
  i -= 65536;
  if (i < 65536){ int n = i / 512, k = i % 512; woutT[i] = f2bf1(Wout[k*128 + n]); return; }
}

// ---------------- node_part = h_V @ W1[:128,:] + b1  (256 blocks, 32 rows) ----
__global__ __launch_bounds__(256,4) void np_kernel(
    const float* __restrict__ hV, const short* __restrict__ w1vT,
    const float* __restrict__ b1, float* __restrict__ npart)
{
  const int row0 = blockIdx.x * 32;
  const int tid = threadIdx.x, lane = tid & 63, wv = tid >> 6;
  __shared__ __attribute__((aligned(16))) short Xs[32][Hh + 8];

  const float4* src = (const float4*)(hV + (size_t)row0 * Hh);
  #pragma unroll
  for (int j = 0; j < 4; ++j){
    int idx = tid + 256*j;
    int r = idx >> 5, c4 = idx & 31;
    float4 v = src[idx];
    *(uint2*)&Xs[r][c4*4] = make_uint2(pk_bf16(v.x,v.y), pk_bf16(v.z,v.w));
  }
  __syncthreads();

  const int arow = lane & 15, kgrp = (lane >> 4) * 8;
  const int col0 = wv * 32, ccol = lane & 15, crow0 = (lane >> 4) * 4;

  f32x4 acc[2][2];
  #pragma unroll
  for (int m = 0; m < 2; ++m) for (int n = 0; n < 2; ++n) acc[m][n] = (f32x4){0.f,0.f,0.f,0.f};

  const short8v* Bw = (const short8v*)w1vT;
  #pragma unroll
  for (int ks = 0; ks < 4; ++ks){
    int kb = ks*32 + kgrp;
    short8v b0 = Bw[(col0 + arow)*16      + (kb >> 3)];
    short8v b1f = Bw[(col0 + 16 + arow)*16 + (kb >> 3)];
    #pragma unroll
    for (int m = 0; m < 2; ++m){
      short8v a = *(const short8v*)&Xs[m*16 + arow][kb];
      acc[m][0] = __builtin_amdgcn_mfma_f32_16x16x32_bf16(a, b0,  acc[m][0], 0,0,0);
      acc[m][1] = __builtin_amdgcn_mfma_f32_16x16x32_bf16(a, b1f, acc[m][1], 0,0,0);
    }
  }
  #pragma unroll
  for (int m = 0; m < 2; ++m) for (int n = 0; n < 2; ++n){
    int colg = col0 + n*16 + ccol;
    float bb = b1[colg];
    #pragma unroll
    for (int r = 0; r < 4; ++r)
      npart[(size_t)(row0 + m*16 + crow0 + r)*Hh + colg] = acc[m][n][r] + bb;
  }
}

// ---------------- edge MLP: K-chunked staging pipeline + collapsed G3 ----------
// One node per 4-wave block, 4 blocks/CU. Stage h_E in 3 chunks of 48x128 cols
// (6 float4/thread = 24 VGPR) so loads for chunk c+1 stay outstanding while
// G1 computes on chunk c (lgkm-only barriers). G3 is collapsed algebraically:
// sum_k m_k(M2_k@W3+b3) = (sum_k m_k M2_k)@W3 + b3*sum(m) -> edge emits the
// 128-float masked sum s per node; dh_kernel does the tiny s@W3.
__global__ __launch_bounds__(256,4) void edge_kernel(
    const float* __restrict__ hE,
    const float* __restrict__ maskA, const float* __restrict__ npart,
    const short* __restrict__ w1p, const short* __restrict__ w2p,
    const float* __restrict__ b2,
    float* __restrict__ sbuf, float* __restrict__ smaskbuf)
{
  const int node = blockIdx.x;
  const int tid = threadIdx.x, lane = tid & 63, wv = tid >> 6;   // wv 0..3
  const int e = lane & 15, q = lane >> 4;
  const int n0 = wv * 32;

  __shared__ __attribute__((aligned(16))) short Et[KN][NINc + 8];  // 48x392 = 37632B
  short (*M1)[136] = (short (*)[136])&Et[0][0];   // aliases Et after read-fence

  const float4* src = (const float4*)(hE + (size_t)node * (KN*NINc));
  float4 pf[6];

  // chunk c covers cols [c*128, c*128+128) of all 48 rows (1536 float4)
  auto LOADC = [&](int c){
    #pragma unroll
    for (int j = 0; j < 6; ++j){
      int idx = tid + 256*j;               // < 1536
      int r = idx >> 5, c4 = idx & 31;
      pf[j] = src[r*96 + c*32 + c4];
    }
  };
  auto STOREC = [&](int c){
    #pragma unroll
    for (int j = 0; j < 6; ++j){
      int idx = tid + 256*j;
      int r = idx >> 5, c4 = idx & 31;
      *(uint2*)&Et[r][c*128 + c4*4] =
        make_uint2(pk_bf16(pf[j].x, pf[j].y), pk_bf16(pf[j].z, pf[j].w));
    }
  };

  // loop-invariant loads (waited per-register at their uses)
  const float4 npv0 = *(const float4*)(npart + (size_t)node*Hh + n0 + 4*q);
  const float4 npv1 = *(const float4*)(npart + (size_t)node*Hh + n0 + 16 + 4*q);
  const float4 b2v0 = *(const float4*)(b2 + n0 + 4*q);
  const float4 b2v1 = *(const float4*)(b2 + n0 + 16 + 4*q);
  const float mk0 = maskA[node*KN + e];
  const float mk1 = maskA[node*KN + 16 + e];
  const float mk2 = maskA[node*KN + 32 + e];

  const f32x4 Z = (f32x4){0.f,0.f,0.f,0.f};
  f32x4 a00=Z, a10=Z, a20=Z, a01=Z, a11=Z, a21=Z;
  const short8v* B1 = (const short8v*)w1p;

  // ---- G1 over chunk c: ks in [4c, 4c+4) ----
  auto G1C = [&](int c){
    #pragma unroll
    for (int kk = 0; kk < 4; ++kk){
      int ks = c*4 + kk;
      short8v f0 = B1[((2*wv  )*12 + ks)*64 + lane];
      short8v f1 = B1[((2*wv+1)*12 + ks)*64 + lane];
      int kb = ks*32 + q*8;
      short8v t0 = *(const short8v*)&Et[e][kb];
      short8v t1 = *(const short8v*)&Et[16 + e][kb];
      short8v t2 = *(const short8v*)&Et[32 + e][kb];
      a00 = __builtin_amdgcn_mfma_f32_16x16x32_bf16(f0, t0, a00, 0,0,0);
      a10 = __builtin_amdgcn_mfma_f32_16x16x32_bf16(f0, t1, a10, 0,0,0);
      a20 = __builtin_amdgcn_mfma_f32_16x16x32_bf16(f0, t2, a20, 0,0,0);
      a01 = __builtin_amdgcn_mfma_f32_16x16x32_bf16(f1, t0, a01, 0,0,0);
      a11 = __builtin_amdgcn_mfma_f32_16x16x32_bf16(f1, t1, a11, 0,0,0);
      a21 = __builtin_amdgcn_mfma_f32_16x16x32_bf16(f1, t2, a21, 0,0,0);
    }
  };

  // ---- chunk-pipelined staging + G1 ----
  LOADC(0);
  STOREC(0);
  LOADC(1);          // outstanding across barrier + G1(0)
  bar_lds();         // chunk0 visible
  G1C(0);
  STOREC(1);         // per-register vmcnt waits (loads had G1(0) to land)
  LOADC(2);
  bar_lds();         // chunk1 visible
  G1C(1);
  STOREC(2);
  bar_lds();         // chunk2 visible
  G1C(2);
  bar_lds();         // READ-FENCE: all Et reads done -> M1 alias region free

  #define WR_M(ACC, ET, COLB, BV)  { short4 s;                      \
    s.x = f2bf1(gelu_f(ACC[0] + BV.x));                             \
    s.y = f2bf1(gelu_f(ACC[1] + BV.y));                             \
    s.z = f2bf1(gelu_f(ACC[2] + BV.z));                             \
    s.w = f2bf1(gelu_f(ACC[3] + BV.w));                             \
    *(short4*)&M1[16*ET + e][COLB + 4*q] = s; }

  WR_M(a00, 0, n0,      npv0)  WR_M(a10, 1, n0,      npv0)
  WR_M(a20, 2, n0,      npv0)  WR_M(a01, 0, n0 + 16, npv1)
  WR_M(a11, 1, n0 + 16, npv1)  WR_M(a21, 2, n0 + 16, npv1)
  #undef WR_M
  bar_lds();         // M1 visible

  // ---- G2 + collapsed-G3 epilogue ----
  {
    f32x4 c00=Z, c10=Z, c20=Z, c01=Z, c11=Z, c21=Z;
    const short8v* B2f = (const short8v*)w2p;
    #pragma unroll
    for (int ks = 0; ks < 4; ++ks){
      short8v f0 = B2f[((2*wv  )*4 + ks)*64 + lane];
      short8v f1 = B2f[((2*wv+1)*4 + ks)*64 + lane];
      int kb = ks*32 + q*8;
      short8v t0 = *(const short8v*)&M1[e][kb];
      short8v t1 = *(const short8v*)&M1[16 + e][kb];
      short8v t2 = *(const short8v*)&M1[32 + e][kb];
      c00 = __builtin_amdgcn_mfma_f32_16x16x32_bf16(f0, t0, c00, 0,0,0);
      c10 = __builtin_amdgcn_mfma_f32_16x16x32_bf16(f0, t1, c10, 0,0,0);
      c20 = __builtin_amdgcn_mfma_f32_16x16x32_bf16(f0, t2, c20, 0,0,0);
      c01 = __builtin_amdgcn_mfma_f32_16x16x32_bf16(f1, t0, c01, 0,0,0);
      c11 = __builtin_amdgcn_mfma_f32_16x16x32_bf16(f1, t1, c11, 0,0,0);
      c21 = __builtin_amdgcn_mfma_f32_16x16x32_bf16(f1, t2, c21, 0,0,0);
    }
    // s[col] = sum_e mask_e * gelu(M2pre[e][col] + b2[col]); butterfly over e
    float sv0[4], sv1[4];
    #pragma unroll
    for (int r = 0; r < 4; ++r){
      sv0[r] = gelu_f(c00[r] + b2v0[r])*mk0 + gelu_f(c10[r] + b2v0[r])*mk1
             + gelu_f(c20[r] + b2v0[r])*mk2;
      sv1[r] = gelu_f(c01[r] + b2v1[r])*mk0 + gelu_f(c11[r] + b2v1[r])*mk1
             + gelu_f(c21[r] + b2v1[r])*mk2;
    }
    float m3 = mk0 + mk1 + mk2;
    #pragma unroll
    for (int s = 1; s <= 8; s <<= 1){
      #pragma unroll
      for (int r = 0; r < 4; ++r){
        sv0[r] += __shfl_xor(sv0[r], s);
        sv1[r] += __shfl_xor(sv1[r], s);
      }
      m3 += __shfl_xor(m3, s);
    }
    if (e == 0){
      float4 o0 = make_float4(sv0[0], sv0[1], sv0[2], sv0[3]);
      float4 o1 = make_float4(sv1[0], sv1[1], sv1[2], sv1[3]);
      *(float4*)(sbuf + (size_t)node*Hh + n0 + 4*q)      = o0;
      *(float4*)(sbuf + (size_t)node*Hh + n0 + 16 + 4*q) = o1;
    }
    if (tid == 0) smaskbuf[node] = m3;
  }
}

// ---------------- dh: out = hV + (S @ W3 + b3*smask)/30  (np-style GEMM) ----
__global__ __launch_bounds__(256,4) void dh_kernel(
    const float* __restrict__ hV, const float* __restrict__ sbuf,
    const float* __restrict__ smaskbuf, const short* __restrict__ w3T,
    const float* __restrict__ b3, float* __restrict__ out)
{
  const int row0 = blockIdx.x * 32;
  const int tid = threadIdx.x, lane = tid & 63, wv = tid >> 6;
  __shared__ __attribute__((aligned(16))) short Ss[32][Hh + 8];
  __shared__ float smS[32];

  const float4* src = (const float4*)(sbuf + (size_t)row0 * Hh);
  #pragma unroll
  for (int j = 0; j < 4; ++j){
    int idx = tid + 256*j;
    int r = idx >> 5, c4 = idx & 31;
    float4 v = src[idx];
    *(uint2*)&Ss[r][c4*4] = make_uint2(pk_bf16(v.x,v.y), pk_bf16(v.z,v.w));
  }
  if (tid < 32) smS[tid] = smaskbuf[row0 + tid];
  __syncthreads();

  const int arow = lane & 15, kgrp = (lane >> 4) * 8;
  const int col0 = wv * 32, ccol = lane & 15, crow0 = (lane >> 4) * 4;

  f32x4 acc[2][2];
  #pragma unroll
  for (int m = 0; m < 2; ++m) for (int n = 0; n < 2; ++n) acc[m][n] = (f32x4){0.f,0.f,0.f,0.f};

  const short8v* Bw = (const short8v*)w3T;
  #pragma unroll
  for (int ks = 0; ks < 4; ++ks){
    int kb = ks*32 + kgrp;
    short8v b0 = Bw[(col0 + arow)*16      + (kb >> 3)];
    short8v b1f = Bw[(col0 + 16 + arow)*16 + (kb >> 3)];
    #pragma unroll
    for (int m = 0; m < 2; ++m){
      short8v a = *(const short8v*)&Ss[m*16 + arow][kb];
      acc[m][0] = __builtin_amdgcn_mfma_f32_16x16x32_bf16(a, b0,  acc[m][0], 0,0,0);
      acc[m][1] = __builtin_amdgcn_mfma_f32_16x16x32_bf16(a, b1f, acc[m][1], 0,0,0);
    }
  }
  #pragma unroll
  for (int m = 0; m < 2; ++m) for (int n = 0; n < 2; ++n){
    int colg = col0 + n*16 + ccol;
    float bb = b3[colg];
    #pragma unroll
    for (int r = 0; r < 4; ++r){
      int rl = m*16 + crow0 + r;
      size_t gi = (size_t)(row0 + rl)*Hh + colg;
      out[gi] = hV[gi] + (acc[m][n][r] + bb*smS[rl]) * (1.0f/30.0f);
    }
  }
}

// ---------------- batched LN1 -> FFN -> LN2 -> mask (in-place on d_out) ----------------
__global__ __launch_bounds__(256,2) void ffn_kernel(
    const float* __restrict__ ln1g, const float* __restrict__ ln1b,
    const short* __restrict__ winT, const float* __restrict__ bin,
    const short* __restrict__ woutT, const float* __restrict__ bout,
    const float* __restrict__ ln2g, const float* __restrict__ ln2b,
    const float* __restrict__ maskV, float* __restrict__ io)
{
  const int row0 = blockIdx.x * 32;
  const int tid = threadIdx.x, lane = tid & 63, wv = tid >> 6;
  __shared__ __attribute__((aligned(16))) short Xs[32][Hh + 8];
  __shared__ __attribute__((aligned(16))) float Rs[32][Hh + 4];
  __shared__ __attribute__((aligned(16))) short Hs[32][FFd + 8];

  const int arow = lane & 15, kgrp = (lane >> 4) * 8;
  const int ccol = lane & 15, crow0 = (lane >> 4) * 4;

  {
    int r = tid >> 3, cb = (tid & 7) * 16;
    const float4* xp = (const float4*)(io + (size_t)(row0 + r)*Hh + cb);
    float xv[16];
    #pragma unroll
    for (int j = 0; j < 4; ++j){
      float4 v = xp[j];
      xv[j*4+0]=v.x; xv[j*4+1]=v.y; xv[j*4+2]=v.z; xv[j*4+3]=v.w;
    }
    float sum = 0.f, sq = 0.f;
    #pragma unroll
    for (int j = 0; j < 16; ++j){ sum += xv[j]; sq += xv[j]*xv[j]; }
    #pragma unroll
    for (int d = 1; d < 8; d <<= 1){ sum += __shfl_xor(sum, d); sq += __shfl_xor(sq, d); }
    float mu = sum * (1.0f/128.0f);
    float var = sq * (1.0f/128.0f) - mu*mu;
    float rstd = rsqrtf(var + 1e-5f);
    #pragma unroll
    for (int j = 0; j < 16; ++j){
      int c = cb + j;
      float xn = (xv[j] - mu) * rstd * ln1g[c] + ln1b[c];
      Xs[r][c] = f2bf1(xn);
      Rs[r][c] = xn;
    }
  }
  __syncthreads();

  {
    f32x4 acc[2][8];
    #pragma unroll
    for (int m = 0; m < 2; ++m) for (int n = 0; n < 8; ++n) acc[m][n] = (f32x4){0.f,0.f,0.f,0.f};
    const short8v* Bw = (const short8v*)winT;
    #pragma unroll
    for (int ks = 0; ks < 4; ++ks){
      int kb = ks*32 + kgrp;
      short8v a0 = *(const short8v*)&Xs[arow][kb];
      short8v a1 = *(const short8v*)&Xs[16 + arow][kb];
      #pragma unroll
      for (int n = 0; n < 8; ++n){
        short8v b = Bw[(wv*128 + n*16 + arow)*16 + (kb >> 3)];
        acc[0][n] = __builtin_amdgcn_mfma_f32_16x16x32_bf16(a0,b,acc[0][n],0,0,0);
        acc[1][n] = __builtin_amdgcn_mfma_f32_16x16x32_bf16(a1,b,acc[1][n],0,0,0);
      }
    }
    #pragma unroll
    for (int m = 0; m < 2; ++m) for (int n = 0; n < 8; ++n){
      int colg = wv*128 + n*16 + ccol;
      float bb = bin[colg];
      #pragma unroll
      for (int r = 0; r < 4; ++r)
        Hs[m*16 + crow0 + r][colg] = f2bf1(gelu_f(acc[m][n][r] + bb));
    }
  }
  __syncthreads();

  {
    f32x4 acc[2][2];
    #pragma unroll
    for (int m = 0; m < 2; ++m) for (int n = 0; n < 2; ++n) acc[m][n] = (f32x4){0.f,0.f,0.f,0.f};
    const short8v* Bw = (const short8v*)woutT;
    #pragma unroll
    for (int ks = 0; ks < 16; ++ks){
      int kb = ks*32 + kgrp;
      short8v a0 = *(const short8v*)&Hs[arow][kb];
      short8v a1 = *(const short8v*)&Hs[16 + arow][kb];
      short8v b0 = Bw[(wv*32 + arow)*64      + (kb >> 3)];
      short8v b1f = Bw[(wv*32 + 16 + arow)*64 + (kb >> 3)];
      acc[0][0] = __builtin_amdgcn_mfma_f32_16x16x32_bf16(a0,b0, acc[0][0],0,0,0);
      acc[1][0] = __builtin_amdgcn_mfma_f32_16x16x32_bf16(a1,b0, acc[1][0],0,0,0);
      acc[0][1] = __builtin_amdgcn_mfma_f32_16x16x32_bf16(a0,b1f,acc[0][1],0,0,0);
      acc[1][1] = __builtin_amdgcn_mfma_f32_16x16x32_bf16(a1,b1f,acc[1][1],0,0,0);
    }
    #pragma unroll
    for (int m = 0; m < 2; ++m) for (int n = 0; n < 2; ++n){
      int colg = wv*32 + n*16 + ccol;
      float bb = bout[colg];
      #pragma unroll
      for (int r = 0; r < 4; ++r){
        int rr = m*16 + crow0 + r;
        Rs[rr][colg] = Rs[rr][colg] + acc[m][n][r] + bb;
      }
    }
  }
  __syncthreads();

  {
    int r = tid >> 3, cb = (tid & 7) * 16;
    float xv[16];
    #pragma unroll
    for (int j = 0; j < 16; ++j) xv[j] = Rs[r][cb + j];
    float sum = 0.f, sq = 0.f;
    #pragma unroll
    for (int j = 0; j < 16; ++j){ sum += xv[j]; sq += xv[j]*xv[j]; }
    #pragma unroll
    for (int d = 1; d < 8; d <<= 1){ sum += __shfl_xor(sum, d); sq += __shfl_xor(sq, d); }
    float mu = sum * (1.0f/128.0f);
    float var = sq * (1.0f/128.0f) - mu*mu;
    float rstd = rsqrtf(var + 1e-5f);
    float mv = maskV[row0 + r];
    float* op = io + (size_t)(row0 + r)*Hh + cb;
    #pragma unroll
    for (int j = 0; j < 4; ++j){
      float4 o;
      o.x = ((xv[j*4+0] - mu)*rstd*ln2g[cb+j*4+0] + ln2b[cb+j*4+0]) * mv;
      o.y = ((xv[j*4+1] - mu)*rstd*ln2g[cb+j*4+1] + ln2b[cb+j*4+1]) * mv;
      o.z = ((xv[j*4+2] - mu)*rstd*ln2g[cb+j*4+2] + ln2b[cb+j*4+2]) * mv;
      o.w = ((xv[j*4+3] - mu)*rstd*ln2g[cb+j*4+3] + ln2b[cb+j*4+3]) * mv;
      ((float4*)op)[j] = o;
    }
  }
}

extern "C" void kernel_launch(void* const* d_in, const int* in_sizes, int n_in,
                              void* d_out, int out_size, void* d_ws, size_t ws_size,
                              hipStream_t stream)
{
  const float* hV    = (const float*)d_in[0];
  const float* hE    = (const float*)d_in[1];
  const float* maskV = (const float*)d_in[2];
  const float* maskA = (const float*)d_in[3];
  const float* W1w   = (const float*)d_in[4];
  const float* W1b   = (const float*)d_in[5];
  const float* W2w   = (const float*)d_in[6];
  const float* W2b   = (const float*)d_in[7];
  const float* W3w   = (const float*)d_in[8];
  const float* W3b   = (const float*)d_in[9];
  const float* Winw  = (const float*)d_in[10];
  const float* Winb  = (const float*)d_in[11];
  const float* Woutw = (const float*)d_in[12];
  const float* Woutb = (const float*)d_in[13];
  const float* l1g   = (const float*)d_in[14];
  const float* l1b   = (const float*)d_in[15];
  const float* l2g   = (const float*)d_in[16];
  const float* l2b   = (const float*)d_in[17];

  char* ws = (char*)d_ws;
  size_t off = 0;
  float* npart = (float*)(ws + off); off += (size_t)NNODE * Hh * 4;
  float* sbuf  = (float*)(ws + off); off += (size_t)NNODE * Hh * 4;
  float* smbuf = (float*)(ws + off); off += (size_t)NNODE * 4;
  short* w1vT  = (short*)(ws + off); off += 16384*2;
  short* w1p   = (short*)(ws + off); off += 49152*2;
  short* w2p   = (short*)(ws + off); off += 16384*2;
  short* w3T   = (short*)(ws + off); off += 16384*2;
  short* winT  = (short*)(ws + off); off += 65536*2;
  short* woutT = (short*)(ws + off); off += 65536*2;
  if (ws_size < off) return;

  prep_weights<<<896, 256, 0, stream>>>(W1w, W2w, W3w, Winw, Woutw,
                                        w1vT, w1p, w2p, w3T, winT, woutT);
  np_kernel<<<NNODE/32, 256, 0, stream>>>(hV, w1vT, W1b, npart);
  edge_kernel<<<NNODE, 256, 0, stream>>>(hE, maskA, npart,
                                         w1p, w2p, W2b, sbuf, smbuf);
  dh_kernel<<<NNODE/32, 256, 0, stream>>>(hV, sbuf, smbuf, w3T, W3b, (float*)d_out);
  ffn_kernel<<<NNODE/32, 256, 0, stream>>>(l1g, l1b, winT, Winb, woutT, Woutb,
                                           l2g, l2b, maskV, (float*)d_out);
}